// Round 7
// baseline (313.171 us; speedup 1.0000x reference)
//
#include <hip/hip_runtime.h>
#include <hip/hip_fp16.h>
#include <math.h>

typedef _Float16 half8 __attribute__((ext_vector_type(8)));
typedef __fp16 fp16x2 __attribute__((ext_vector_type(2)));
typedef float f32x4 __attribute__((ext_vector_type(4)));

#define BATCH 1024
#define IN_DIM 4096
#define HV 8192
#define NTAP 40          // 39 gates -> degree-39 polynomial -> 40 taps

#define BM 128
#define BN 128
#define BK 32
#define BKP 36           // f32 fallback LDS row stride

// pipelined gemm geometry
#define BM2 128
#define BN2 256
#define BK2 64
#define NT2 (IN_DIM / BK2)       // 64 K-tiles
#define ASZ (BM2 * BK2)          // 8192 f16 (16 KB)
#define BSZ (BN2 * BK2)          // 16384 f16 (32 KB)
#define TSZ (ASZ + BSZ)          // 24576 f16 (48 KB) per buffer

#define GLD16(g, l) __builtin_amdgcn_global_load_lds(                          \
    (const __attribute__((address_space(1))) void*)(g),                        \
    (__attribute__((address_space(3))) void*)(l), 16, 0, 0)

// pack 8 f32 -> 8 f16 (RTZ), 4 VALU instrs (fallback path only)
static __device__ __forceinline__ half8 pk8(f32x4 a, f32x4 b) {
    union { fp16x2 p[4]; half8 h; } u;
    u.p[0] = __builtin_amdgcn_cvt_pkrtz(a.x, a.y);
    u.p[1] = __builtin_amdgcn_cvt_pkrtz(a.z, a.w);
    u.p[2] = __builtin_amdgcn_cvt_pkrtz(b.x, b.y);
    u.p[3] = __builtin_amdgcn_cvt_pkrtz(b.z, b.w);
    return u.h;
}

// ---------------- f32 -> f16 conversion (RNE) ----------------
typedef _Float16 half4v __attribute__((ext_vector_type(4)));
__global__ __launch_bounds__(256) void cvt_f32_f16(const float4* __restrict__ src,
                                                   half4v* __restrict__ dst, int n4) {
    int i = blockIdx.x * 256 + threadIdx.x;
    if (i < n4) {
        float4 v = src[i];
        half4v h;
        h.x = (_Float16)v.x; h.y = (_Float16)v.y;
        h.z = (_Float16)v.z; h.w = (_Float16)v.w;
        dst[i] = h;
    }
}

// ---------------- gate-polynomial taps, computed once (1 block, 1 wave) ----------------
__global__ __launch_bounds__(64) void compute_taps(const float* __restrict__ qp,
                                                   float* __restrict__ taps) {
    const int lane = threadIdx.x;
    float qv = (lane < 39) ? qp[lane] : 0.f;
    float pr = (lane == 0) ? 1.f : 0.f;
    float pim = 0.f;
    for (int t = 0; t < 39; t++) {
        float a = __shfl(qv, t, 64) * 0.5f;
        float c = cosf(a), s = sinf(a);
        float ur = __shfl_up(pr, 1, 64);
        float ui = __shfl_up(pim, 1, 64);
        if (lane == 0) { ur = 0.f; ui = 0.f; }
        float nr = c * pr - s * ui;
        float ni = c * pim + s * ur;
        pr = nr; pim = ni;
    }
    if (lane < NTAP) taps[lane] = pr;       // only real parts needed downstream
}

// ---------------- primary GEMM: 4-phase interleave + counted-vmcnt triple buffer ------
// 128(M) x 256(N) tile, BK=64, 512 threads = 8 waves (2M x 4N), 64x64 per wave.
// Grid 32x8 = 256 blocks = 1/CU.  LDS 3 x 48 KB; 2 K-tiles of loads always in flight.
// Phase structure (m196/m201): each K-tile = 4 quadrant phases
//   { ds_read frags -> s_barrier -> setprio+8 MFMA -> s_barrier }
// so staggered waves keep LDS and MFMA pipes simultaneously busy.
// RACE FIX (R6 post-mortem): vmcnt only tracks the ISSUING wave's DMA loads, so the
// gate for tile t+1 must be followed by a barrier before ANY wave reads tile t+1.
// The gate therefore sits at the END of iteration t (P3, before the final barrier):
// final barrier doubles as "all waves confirmed tile t+1 landed".  Prologue gates
// tile 0 with vmcnt(6)+barrier.  vmcnt never drains to 0 until the last tiles (T4).
// Hazards: STAGE(t+2) (issued P0 of t) targets buf (t-1)%3 whose last reads completed
// (MFMA data-dep) before t-1's final barrier; gate at P3 has 12 outstanding loads,
// vmcnt(6) -> stage(t+1)'s 6 landed.  All barriers uniform.
// LDS swizzle (R1/R5-verified, conflicts = 0): physical 16B slot = logical ^ (row&7);
// GLD16 dest linear, global source inverse-swizzled (rule #21).
__global__ __launch_bounds__(512, 2) void gemm_f16(
        const _Float16* __restrict__ A,   // [BATCH][IN_DIM] f16
        const _Float16* __restrict__ B,   // [HV][IN_DIM]   f16
        float* __restrict__ out,          // classical [BATCH][HV]
        long out_n) {
    __shared__ __align__(16) _Float16 lds[3 * TSZ];   // 144 KB

    const int tid  = threadIdx.x;
    const int lane = tid & 63;
    const int wave = tid >> 6;          // 0..7
    const int wm = wave & 1;            // 2 waves in M (64 rows each)
    const int wn = wave >> 1;           // 4 waves in N (64 cols each)
    const int q = lane >> 4, r = lane & 15;
    const int bm = blockIdx.y * BM2;
    const int bn = blockIdx.x * BN2;

    // ---- staging addresses (fixed per thread; += k0 per tile) ----
    // slot p -> row R=p>>3, physical slot s=p&7 holds source chunk c = s ^ (R&7)
    const _Float16* srcA[2];
    int dA[2];
    #pragma unroll
    for (int h = 0; h < 2; h++) {
        const int p = h * 512 + tid;
        const int R = p >> 3, c = (p & 7) ^ (R & 7);
        srcA[h] = A + (size_t)(bm + R) * IN_DIM + c * 8;
        dA[h] = (h * 512 + wave * 64) * 8;           // wave-uniform; HW adds lane*16B
    }
    const _Float16* srcB[4];
    int dB[4];
    #pragma unroll
    for (int h = 0; h < 4; h++) {
        const int p = h * 512 + tid;
        const int R = p >> 3, c = (p & 7) ^ (R & 7);
        srcB[h] = B + (size_t)(bn + R) * IN_DIM + c * 8;
        dB[h] = ASZ + (h * 512 + wave * 64) * 8;
    }

    f32x4 acc[4][4] = {};

#define STAGE(u, k0)  do {                                   \
        _Float16* bpS = &lds[(u) * TSZ];                     \
        GLD16(srcA[0] + (k0), bpS + dA[0]);                  \
        GLD16(srcA[1] + (k0), bpS + dA[1]);                  \
        GLD16(srcB[0] + (k0), bpS + dB[0]);                  \
        GLD16(srcB[1] + (k0), bpS + dB[1]);                  \
        GLD16(srcB[2] + (k0), bpS + dB[2]);                  \
        GLD16(srcB[3] + (k0), bpS + dB[3]);                  \
    } while (0)

    // fragment reads: row R (stride 64 f16), logical slot s=kk*4+q, physical s^(r&7)
#define RD_A(dst, kk)  do {                                                        \
        _Pragma("unroll")                                                          \
        for (int i = 0; i < 4; i++) {                                              \
            const int R = wm * 64 + i * 16 + r;                                    \
            const int sw = ((kk) * 4 + q) ^ (r & 7);                               \
            dst[i] = *(const half8*)&bp[R * 64 + sw * 8];                          \
        }                                                                          \
    } while (0)
#define RD_B(dst, kk, jh)  do {                                                    \
        _Pragma("unroll")                                                          \
        for (int jj = 0; jj < 2; jj++) {                                           \
            const int R = wn * 64 + ((jh) * 2 + jj) * 16 + r;                      \
            const int sw = ((kk) * 4 + q) ^ (r & 7);                               \
            dst[jj] = *(const half8*)&bp[ASZ + R * 64 + sw * 8];                   \
        }                                                                          \
    } while (0)
#define MFMA8(afv, bfv, jh)  do {                                                  \
        __builtin_amdgcn_s_setprio(1);                                             \
        _Pragma("unroll")                                                          \
        for (int i = 0; i < 4; i++)                                                \
            _Pragma("unroll")                                                      \
            for (int jj = 0; jj < 2; jj++)                                         \
                acc[i][(jh) * 2 + jj] = __builtin_amdgcn_mfma_f32_16x16x32_f16(    \
                    afv[i], bfv[jj], acc[i][(jh) * 2 + jj], 0, 0, 0);              \
        __builtin_amdgcn_s_setprio(0);                                             \
    } while (0)

    STAGE(0, 0);
    STAGE(1, BK2);
    // gate tile 0 for ALL waves: own vmcnt + barrier (vmcnt is per-wave only!)
    asm volatile("s_waitcnt vmcnt(6)" ::: "memory");
    __builtin_amdgcn_sched_barrier(0);
    __builtin_amdgcn_s_barrier();

    int cur = 0;
    for (int t = 0; t < NT2; ++t) {
        const _Float16* bp = &lds[cur * TSZ];
        half8 afA[4], afB[4], bf[2];

        // ---- P0: read A(kk0)+B01(kk0); issue stage(t+2) ----
        RD_A(afA, 0);
        RD_B(bf, 0, 0);
        if (t + 2 < NT2) {
            const int nxt = (cur + 2 >= 3) ? cur - 1 : cur + 2;
            STAGE(nxt, (t + 2) * BK2);
        }
        __builtin_amdgcn_s_barrier();
        MFMA8(afA, bf, 0);
        __builtin_amdgcn_s_barrier();

        // ---- P1: read B23(kk0) ----
        RD_B(bf, 0, 1);
        __builtin_amdgcn_s_barrier();
        MFMA8(afA, bf, 1);
        __builtin_amdgcn_s_barrier();

        // ---- P2: read A(kk1)+B01(kk1) ----
        RD_A(afB, 1);
        RD_B(bf, 1, 0);
        __builtin_amdgcn_s_barrier();
        MFMA8(afB, bf, 0);
        __builtin_amdgcn_s_barrier();

        // ---- P3: read B23(kk1); gate tile t+1 BEFORE the final barrier ----
        RD_B(bf, 1, 1);
        if (t + 1 < NT2) {
            if (t + 2 < NT2) { asm volatile("s_waitcnt vmcnt(6)" ::: "memory"); }
            else             { asm volatile("s_waitcnt vmcnt(0)" ::: "memory"); }
            __builtin_amdgcn_sched_barrier(0);
        }
        __builtin_amdgcn_s_barrier();
        MFMA8(afB, bf, 1);
        __builtin_amdgcn_s_barrier();   // doubles as "tile t+1 landed for all waves"

        cur = (cur + 1 == 3) ? 0 : cur + 1;
    }
#undef STAGE
#undef RD_A
#undef RD_B
#undef MFMA8

    // C/D layout: col = lane&15, row = (lane>>4)*4 + reg.  Guarded stores.
    #pragma unroll
    for (int i = 0; i < 4; i++) {
        const int row = bm + wm * 64 + i * 16 + q * 4;
        #pragma unroll
        for (int j = 0; j < 4; j++) {
            const int col = bn + wn * 64 + j * 16 + r;
            #pragma unroll
            for (int reg = 0; reg < 4; reg++) {
                long idx = (long)(row + reg) * HV + col;
                if (idx < out_n) out[idx] = acc[i][j][reg];
            }
        }
    }
}

// ---------------- fallback GEMM: f32 inputs, register staging (R6, proven) ----------------
__global__ __launch_bounds__(256) void gemm_f32in(
        const float* __restrict__ A, const float* __restrict__ B,
        float* __restrict__ out, long out_n) {
    __shared__ __align__(16) float lgA[BM * BKP];
    __shared__ __align__(16) float lgB[BN * BKP];

    const int tid  = threadIdx.x;
    const int lane = tid & 63;
    const int wave = tid >> 6;
    const int wm = wave & 1, wn = wave >> 1;
    const int q = lane >> 4, r = lane & 15;
    const int bm = blockIdx.y * BM;
    const int bn = blockIdx.x * BN;

    const int rg = lane >> 3;
    const int cg = (lane & 7) * 4;
    const float* gA = A + (size_t)(bm + wave * 32 + rg) * IN_DIM + cg;
    const float* gB = B + (size_t)(bn + wave * 32 + rg) * IN_DIM + cg;
    float* lA = &lgA[(wave * 32 + rg) * BKP + cg];
    float* lB = &lgB[(wave * 32 + rg) * BKP + cg];

    f32x4 acc[4][4] = {};

    for (int k0 = 0; k0 < IN_DIM; k0 += BK) {
        float4 va[4], vb[4];
        #pragma unroll
        for (int i = 0; i < 4; i++) {
            va[i] = *(const float4*)(gA + k0 + (size_t)(8 * i) * IN_DIM);
            vb[i] = *(const float4*)(gB + k0 + (size_t)(8 * i) * IN_DIM);
        }
        __syncthreads();
        #pragma unroll
        for (int i = 0; i < 4; i++) {
            *(float4*)(lA + 8 * i * BKP) = va[i];
            *(float4*)(lB + 8 * i * BKP) = vb[i];
        }
        __syncthreads();

        half8 af[4], bf[4];
        #pragma unroll
        for (int i = 0; i < 4; i++) {
            const float* p = &lgA[(wm * 64 + i * 16 + r) * BKP + q * 8];
            af[i] = pk8(*(const f32x4*)p, *(const f32x4*)(p + 4));
        }
        #pragma unroll
        for (int j = 0; j < 4; j++) {
            const float* p = &lgB[(wn * 64 + j * 16 + r) * BKP + q * 8];
            bf[j] = pk8(*(const f32x4*)p, *(const f32x4*)(p + 4));
        }

        #pragma unroll
        for (int i = 0; i < 4; i++)
            #pragma unroll
            for (int j = 0; j < 4; j++)
                acc[i][j] = __builtin_amdgcn_mfma_f32_16x16x32_f16(af[i], bf[j], acc[i][j], 0, 0, 0);
    }

    #pragma unroll
    for (int i = 0; i < 4; i++) {
        const int row = bm + wm * 64 + i * 16 + q * 4;
        #pragma unroll
        for (int j = 0; j < 4; j++) {
            const int col = bn + wn * 64 + j * 16 + r;
            #pragma unroll
            for (int reg = 0; reg < 4; reg++) {
                long idx = (long)(row + reg) * HV + col;
                if (idx < out_n) out[idx] = acc[i][j][reg];
            }
        }
    }
}

// ---------------- fused normalize + real-part 40-tap circular conv, in place ----------------
// 32 contiguous outputs/thread -> LDS reads 2.25 floats/output; XOR-swizzled LDS;
// taps broadcast from LDS; inv folded at store.  (R4: verified)
#define SW4(p4) ((p4) ^ (((p4) >> 3) & 7))
__global__ __launch_bounds__(256) void norm_conv(float* __restrict__ out,
                                                 const float* __restrict__ qp,
                                                 const float* __restrict__ taps,
                                                 long out_n) {
    __shared__ __align__(16) float ldsv[40 + HV + 24];   // logical [p] = row[(p-40) mod HV]
    __shared__ float scr[NTAP];
    __shared__ float red[4];

    const int b = blockIdx.x;
    if ((long)(b + 1) * HV > out_n) return;

    const int tid = threadIdx.x;
    const int lane = tid & 63;
    const int wave = tid >> 6;
    float* rowp = out + (size_t)b * HV;
    const float4* row4 = (const float4*)rowp;
    float4* l4 = (float4*)ldsv;

    float ss = 0.f;
    #pragma unroll
    for (int it = 0; it < 8; it++) {
        int j = it * 256 + tid;
        float4 v = row4[j];
        ss += v.x * v.x + v.y * v.y + v.z * v.z + v.w * v.w;
        l4[SW4(10 + j)] = v;                    // logical float4 index 10+j, swizzled
    }
    if (tid < NTAP) {                           // circular halo: logical p = tid (0..39)
        ldsv[(SW4(tid >> 2) << 2) | (tid & 3)] = rowp[HV - NTAP + tid];
    }

    #pragma unroll
    for (int off = 32; off > 0; off >>= 1) ss += __shfl_down(ss, off, 64);
    if (lane == 0) red[wave] = ss;

    if (taps) {
        if (tid < NTAP) scr[tid] = taps[tid];   // precomputed by compute_taps
    } else if (wave == 0) {
        float qv = (lane < 39) ? qp[lane] : 0.f;
        float pr = (lane == 0) ? 1.f : 0.f;
        float pim = 0.f;
        for (int t = 0; t < 39; t++) {
            float a = __shfl(qv, t, 64) * 0.5f;
            float c = cosf(a), s = sinf(a);
            float ur = __shfl_up(pr, 1, 64);
            float ui = __shfl_up(pim, 1, 64);
            if (lane == 0) { ur = 0.f; ui = 0.f; }
            float nr = c * pr - s * ui;
            float ni = c * pim + s * ur;
            pr = nr; pim = ni;
        }
        if (lane < NTAP) scr[lane] = pr;
    }
    __syncthreads();

    const float inv = 1.0f / sqrtf(red[0] + red[1] + red[2] + red[3]);

    // window: logical ldsv[i0 .. i0+71] covers in[i0-40 .. i0+31]; out[i0+o] needs w[40+o-k]
    float w[72];
    #pragma unroll
    for (int t = 0; t < 18; t++) ((float4*)w)[t] = l4[SW4(8 * tid + t)];

    float4* out4 = (float4*)rowp;
    #pragma unroll
    for (int h = 0; h < 2; h++) {               // two half-passes keep VGPR ~100
        float av[16] = {};
        #pragma unroll
        for (int k = 0; k < NTAP; k++) {
            const float c = scr[k];             // LDS broadcast (free)
            #pragma unroll
            for (int o = 0; o < 16; o++) av[o] += c * w[40 + h * 16 + o - k];
        }
        #pragma unroll
        for (int t = 0; t < 4; t++) {
            out4[8 * tid + 4 * h + t] = make_float4(inv * av[4 * t], inv * av[4 * t + 1],
                                                    inv * av[4 * t + 2], inv * av[4 * t + 3]);
        }
    }
}

// ---------------- launch ----------------
extern "C" void kernel_launch(void* const* d_in, const int* in_sizes, int n_in,
                              void* d_out, int out_size, void* d_ws, size_t ws_size,
                              hipStream_t stream) {
    const float* x  = (const float*)d_in[0];   // [1024][4096]
    const float* W  = (const float*)d_in[1];   // [8192][4096]
    const float* qp = (const float*)d_in[2];   // [39]
    float* out = (float*)d_out;                // [1024][8192] floats (Re of amps)
    long out_n = (long)out_size;

    const size_t need = (size_t)BATCH * IN_DIM * 2 + (size_t)HV * IN_DIM * 2;  // 72 MB

    if (ws_size >= need) {
        _Float16* xh = (_Float16*)d_ws;
        _Float16* wh = xh + (size_t)BATCH * IN_DIM;
        float* taps = nullptr;
        if (ws_size >= need + 256) {
            taps = (float*)((char*)d_ws + need);
            compute_taps<<<1, 64, 0, stream>>>(qp, taps);
        }
        int n4x = BATCH * IN_DIM / 4;          // 1,048,576
        int n4w = HV * IN_DIM / 4;             // 8,388,608
        cvt_f32_f16<<<n4x / 256, 256, 0, stream>>>((const float4*)x, (half4v*)xh, n4x);
        cvt_f32_f16<<<n4w / 256, 256, 0, stream>>>((const float4*)W, (half4v*)wh, n4w);
        dim3 grid2(HV / BN2, BATCH / BM2);     // (32, 8) = 256 blocks = 1/CU
        gemm_f16<<<grid2, 512, 0, stream>>>(xh, wh, out, out_n);
        norm_conv<<<BATCH, 256, 0, stream>>>(out, qp, taps, out_n);
    } else {
        float* taps = nullptr;
        if (ws_size >= 256) {
            taps = (float*)d_ws;
            compute_taps<<<1, 64, 0, stream>>>(qp, taps);
        }
        dim3 grid(HV / BN, BATCH / BM);        // (64, 8)
        gemm_f32in<<<grid, 256, 0, stream>>>(x, W, out, out_n);
        norm_conv<<<BATCH, 256, 0, stream>>>(out, qp, taps, out_n);
    }
}

// Round 8
// 307.918 us; speedup vs baseline: 1.0171x; 1.0171x over previous
//
#include <hip/hip_runtime.h>
#include <hip/hip_fp16.h>
#include <math.h>

typedef _Float16 half8 __attribute__((ext_vector_type(8)));
typedef __fp16 fp16x2 __attribute__((ext_vector_type(2)));
typedef float f32x4 __attribute__((ext_vector_type(4)));

#define BATCH 1024
#define IN_DIM 4096
#define HV 8192
#define NTAP 40          // 39 gates -> degree-39 polynomial -> 40 taps

#define BM 128
#define BN 128
#define BK 32
#define BKP 36           // f32 fallback LDS row stride

// pipelined gemm geometry
#define BM2 128
#define BN2 256
#define BK2 64
#define NT2 (IN_DIM / BK2)       // 64 K-tiles
#define ASZ (BM2 * BK2)          // 8192 f16 (16 KB)
#define BSZ (BN2 * BK2)          // 16384 f16 (32 KB)
#define TSZ (ASZ + BSZ)          // 24576 f16 (48 KB) per buffer

#define GLD16(g, l) __builtin_amdgcn_global_load_lds(                          \
    (const __attribute__((address_space(1))) void*)(g),                        \
    (__attribute__((address_space(3))) void*)(l), 16, 0, 0)

// pack 8 f32 -> 8 f16 (RTZ), 4 VALU instrs (fallback path only)
static __device__ __forceinline__ half8 pk8(f32x4 a, f32x4 b) {
    union { fp16x2 p[4]; half8 h; } u;
    u.p[0] = __builtin_amdgcn_cvt_pkrtz(a.x, a.y);
    u.p[1] = __builtin_amdgcn_cvt_pkrtz(a.z, a.w);
    u.p[2] = __builtin_amdgcn_cvt_pkrtz(b.x, b.y);
    u.p[3] = __builtin_amdgcn_cvt_pkrtz(b.z, b.w);
    return u.h;
}

// ---------------- f32 -> f16 conversion (RNE) ----------------
typedef _Float16 half4v __attribute__((ext_vector_type(4)));
__global__ __launch_bounds__(256) void cvt_f32_f16(const float4* __restrict__ src,
                                                   half4v* __restrict__ dst, int n4) {
    int i = blockIdx.x * 256 + threadIdx.x;
    if (i < n4) {
        float4 v = src[i];
        half4v h;
        h.x = (_Float16)v.x; h.y = (_Float16)v.y;
        h.z = (_Float16)v.z; h.w = (_Float16)v.w;
        dst[i] = h;
    }
}

// ---------------- gate-polynomial taps, computed once (1 block, 1 wave) ----------------
__global__ __launch_bounds__(64) void compute_taps(const float* __restrict__ qp,
                                                   float* __restrict__ taps) {
    const int lane = threadIdx.x;
    float qv = (lane < 39) ? qp[lane] : 0.f;
    float pr = (lane == 0) ? 1.f : 0.f;
    float pim = 0.f;
    for (int t = 0; t < 39; t++) {
        float a = __shfl(qv, t, 64) * 0.5f;
        float c = cosf(a), s = sinf(a);
        float ur = __shfl_up(pr, 1, 64);
        float ui = __shfl_up(pim, 1, 64);
        if (lane == 0) { ur = 0.f; ui = 0.f; }
        float nr = c * pr - s * ui;
        float ni = c * pim + s * ur;
        pr = nr; pim = ni;
    }
    if (lane < NTAP) taps[lane] = pr;       // only real parts needed downstream
}

// ---------------- primary GEMM: counted-vmcnt triple-buffer pipeline (R5, verified) ----
// 128(M) x 256(N) tile, BK=64, 512 threads = 8 waves (2M x 4N), 64x64 per wave.
// Grid 32x8 = 256 blocks = 1/CU.  LDS 3 x 48 KB; 2 K-tiles of loads in flight.
// s_waitcnt vmcnt(6) -> barrier -> STAGE(t+2) -> ds_read+MFMA(t).  Measured 82.7 us,
// MfmaUtil 35.5%, conflicts 0 (R5).  R7's 4-phase split regressed (86 us) -> reverted.
__global__ __launch_bounds__(512, 2) void gemm_f16(
        const _Float16* __restrict__ A,   // [BATCH][IN_DIM] f16
        const _Float16* __restrict__ B,   // [HV][IN_DIM]   f16
        float* __restrict__ out,          // classical [BATCH][HV]
        long out_n) {
    __shared__ __align__(16) _Float16 lds[3 * TSZ];   // 144 KB

    const int tid  = threadIdx.x;
    const int lane = tid & 63;
    const int wave = tid >> 6;          // 0..7
    const int wm = wave & 1;            // 2 waves in M (64 rows each)
    const int wn = wave >> 1;           // 4 waves in N (64 cols each)
    const int q = lane >> 4, r = lane & 15;
    const int bm = blockIdx.y * BM2;
    const int bn = blockIdx.x * BN2;

    // ---- staging addresses (fixed per thread; += k0 per tile) ----
    // slot p -> row R=p>>3, physical slot s=p&7 holds source chunk c = s ^ (R&7)
    const _Float16* srcA[2];
    int dA[2];
    #pragma unroll
    for (int h = 0; h < 2; h++) {
        const int p = h * 512 + tid;
        const int R = p >> 3, c = (p & 7) ^ (R & 7);
        srcA[h] = A + (size_t)(bm + R) * IN_DIM + c * 8;
        dA[h] = (h * 512 + wave * 64) * 8;           // wave-uniform; HW adds lane*16B
    }
    const _Float16* srcB[4];
    int dB[4];
    #pragma unroll
    for (int h = 0; h < 4; h++) {
        const int p = h * 512 + tid;
        const int R = p >> 3, c = (p & 7) ^ (R & 7);
        srcB[h] = B + (size_t)(bn + R) * IN_DIM + c * 8;
        dB[h] = ASZ + (h * 512 + wave * 64) * 8;
    }

    f32x4 acc[4][4] = {};

#define STAGE(u, k0)  do {                                   \
        _Float16* bp = &lds[(u) * TSZ];                      \
        GLD16(srcA[0] + (k0), bp + dA[0]);                   \
        GLD16(srcA[1] + (k0), bp + dA[1]);                   \
        GLD16(srcB[0] + (k0), bp + dB[0]);                   \
        GLD16(srcB[1] + (k0), bp + dB[1]);                   \
        GLD16(srcB[2] + (k0), bp + dB[2]);                   \
        GLD16(srcB[3] + (k0), bp + dB[3]);                   \
    } while (0)

    // fragment LDS offsets: row R (stride 64 f16), logical slot s=kk*4+q,
    // physical slot s^(R&7) = s^(r&7) since 64|wm*64 and 16|i*16.
#define COMPUTE(u)  do {                                                            \
        const _Float16* bp = &lds[(u) * TSZ];                                       \
        half8 af[4][2], bf[4][2];                                                   \
        _Pragma("unroll")                                                           \
        for (int i = 0; i < 4; i++)                                                 \
            _Pragma("unroll")                                                       \
            for (int kk = 0; kk < 2; kk++) {                                        \
                const int R = wm * 64 + i * 16 + r;                                 \
                const int sw = (kk * 4 + q) ^ (r & 7);                              \
                af[i][kk] = *(const half8*)&bp[R * 64 + sw * 8];                    \
            }                                                                       \
        _Pragma("unroll")                                                           \
        for (int j = 0; j < 4; j++)                                                 \
            _Pragma("unroll")                                                       \
            for (int kk = 0; kk < 2; kk++) {                                        \
                const int R = wn * 64 + j * 16 + r;                                 \
                const int sw = (kk * 4 + q) ^ (r & 7);                              \
                bf[j][kk] = *(const half8*)&bp[ASZ + R * 64 + sw * 8];              \
            }                                                                       \
        __builtin_amdgcn_s_setprio(1);                                              \
        _Pragma("unroll")                                                           \
        for (int i = 0; i < 4; i++)                                                 \
            _Pragma("unroll")                                                       \
            for (int j = 0; j < 4; j++)                                             \
                _Pragma("unroll")                                                   \
                for (int kk = 0; kk < 2; kk++)                                      \
                    acc[i][j] = __builtin_amdgcn_mfma_f32_16x16x32_f16(             \
                        af[i][kk], bf[j][kk], acc[i][j], 0, 0, 0);                  \
        __builtin_amdgcn_s_setprio(0);                                              \
    } while (0)

    STAGE(0, 0);
    STAGE(1, BK2);
    int cur = 0;
    for (int t = 0; t < NT2 - 1; ++t) {
        asm volatile("s_waitcnt vmcnt(6)" ::: "memory");   // tile t landed; t+1 in flight
        __builtin_amdgcn_sched_barrier(0);
        __builtin_amdgcn_s_barrier();
        if (t + 2 < NT2) {
            const int nxt = (cur + 2 >= 3) ? cur - 1 : cur + 2;
            STAGE(nxt, (t + 2) * BK2);
        }
        COMPUTE(cur);
        cur = (cur + 1 == 3) ? 0 : cur + 1;
    }
    asm volatile("s_waitcnt vmcnt(0)" ::: "memory");       // final tile fully staged
    __builtin_amdgcn_sched_barrier(0);
    __builtin_amdgcn_s_barrier();
    COMPUTE(cur);
#undef STAGE
#undef COMPUTE

    // C/D layout: col = lane&15, row = (lane>>4)*4 + reg.  Guarded stores.
    #pragma unroll
    for (int i = 0; i < 4; i++) {
        const int row = bm + wm * 64 + i * 16 + q * 4;
        #pragma unroll
        for (int j = 0; j < 4; j++) {
            const int col = bn + wn * 64 + j * 16 + r;
            #pragma unroll
            for (int reg = 0; reg < 4; reg++) {
                long idx = (long)(row + reg) * HV + col;
                if (idx < out_n) out[idx] = acc[i][j][reg];
            }
        }
    }
}

// ---------------- fallback GEMM: f32 inputs, register staging (R6, proven) ----------------
__global__ __launch_bounds__(256) void gemm_f32in(
        const float* __restrict__ A, const float* __restrict__ B,
        float* __restrict__ out, long out_n) {
    __shared__ __align__(16) float lgA[BM * BKP];
    __shared__ __align__(16) float lgB[BN * BKP];

    const int tid  = threadIdx.x;
    const int lane = tid & 63;
    const int wave = tid >> 6;
    const int wm = wave & 1, wn = wave >> 1;
    const int q = lane >> 4, r = lane & 15;
    const int bm = blockIdx.y * BM;
    const int bn = blockIdx.x * BN;

    const int rg = lane >> 3;
    const int cg = (lane & 7) * 4;
    const float* gA = A + (size_t)(bm + wave * 32 + rg) * IN_DIM + cg;
    const float* gB = B + (size_t)(bn + wave * 32 + rg) * IN_DIM + cg;
    float* lA = &lgA[(wave * 32 + rg) * BKP + cg];
    float* lB = &lgB[(wave * 32 + rg) * BKP + cg];

    f32x4 acc[4][4] = {};

    for (int k0 = 0; k0 < IN_DIM; k0 += BK) {
        float4 va[4], vb[4];
        #pragma unroll
        for (int i = 0; i < 4; i++) {
            va[i] = *(const float4*)(gA + k0 + (size_t)(8 * i) * IN_DIM);
            vb[i] = *(const float4*)(gB + k0 + (size_t)(8 * i) * IN_DIM);
        }
        __syncthreads();
        #pragma unroll
        for (int i = 0; i < 4; i++) {
            *(float4*)(lA + 8 * i * BKP) = va[i];
            *(float4*)(lB + 8 * i * BKP) = vb[i];
        }
        __syncthreads();

        half8 af[4], bf[4];
        #pragma unroll
        for (int i = 0; i < 4; i++) {
            const float* p = &lgA[(wm * 64 + i * 16 + r) * BKP + q * 8];
            af[i] = pk8(*(const f32x4*)p, *(const f32x4*)(p + 4));
        }
        #pragma unroll
        for (int j = 0; j < 4; j++) {
            const float* p = &lgB[(wn * 64 + j * 16 + r) * BKP + q * 8];
            bf[j] = pk8(*(const f32x4*)p, *(const f32x4*)(p + 4));
        }

        #pragma unroll
        for (int i = 0; i < 4; i++)
            #pragma unroll
            for (int j = 0; j < 4; j++)
                acc[i][j] = __builtin_amdgcn_mfma_f32_16x16x32_f16(af[i], bf[j], acc[i][j], 0, 0, 0);
    }

    #pragma unroll
    for (int i = 0; i < 4; i++) {
        const int row = bm + wm * 64 + i * 16 + q * 4;
        #pragma unroll
        for (int j = 0; j < 4; j++) {
            const int col = bn + wn * 64 + j * 16 + r;
            #pragma unroll
            for (int reg = 0; reg < 4; reg++) {
                long idx = (long)(row + reg) * HV + col;
                if (idx < out_n) out[idx] = acc[i][j][reg];
            }
        }
    }
}

// ---------------- fused normalize + real-part 40-tap circular conv, in place ----------------
// R8 REWRITE (scratch-proof): the previous versions held the conv window in
// float w[72] accessed via (float4*) casts + deep-unrolled runtime-looking indices --
// if SROA/unroll fails the window lands in SCRATCH (rule #20) => ~100+ us.  Now:
// 4 groups x 8 outputs/thread; window = float4 w4[12]; element access via a
// constant-folding component ternary (WEL) -> registers even if unrolling degrades.
#define SW4(p4) ((p4) ^ (((p4) >> 3) & 7))
#define WEL(u) (((u) & 3) == 0 ? w4[(u) >> 2].x : ((u) & 3) == 1 ? w4[(u) >> 2].y : \
                ((u) & 3) == 2 ? w4[(u) >> 2].z : w4[(u) >> 2].w)
__global__ __launch_bounds__(256, 2) void norm_conv(float* __restrict__ out,
                                                    const float* __restrict__ qp,
                                                    const float* __restrict__ taps,
                                                    long out_n) {
    __shared__ __align__(16) float ldsv[40 + HV + 24];   // logical [p] = row[(p-40) mod HV]
    __shared__ float scr[NTAP];
    __shared__ float red[4];

    const int b = blockIdx.x;
    if ((long)(b + 1) * HV > out_n) return;

    const int tid = threadIdx.x;
    const int lane = tid & 63;
    const int wave = tid >> 6;
    float* rowp = out + (size_t)b * HV;
    const float4* row4 = (const float4*)rowp;
    float4* l4 = (float4*)ldsv;

    float ss = 0.f;
    #pragma unroll
    for (int it = 0; it < 8; it++) {
        int j = it * 256 + tid;
        float4 v = row4[j];
        ss += v.x * v.x + v.y * v.y + v.z * v.z + v.w * v.w;
        l4[SW4(10 + j)] = v;                    // logical float4 index 10+j, swizzled
    }
    if (tid < NTAP) {                           // circular halo: logical p = tid (0..39)
        ldsv[(SW4(tid >> 2) << 2) | (tid & 3)] = rowp[HV - NTAP + tid];
    }

    #pragma unroll
    for (int off = 32; off > 0; off >>= 1) ss += __shfl_down(ss, off, 64);
    if (lane == 0) red[wave] = ss;

    if (taps) {
        if (tid < NTAP) scr[tid] = taps[tid];   // precomputed by compute_taps
    } else if (wave == 0) {
        float qv = (lane < 39) ? qp[lane] : 0.f;
        float pr = (lane == 0) ? 1.f : 0.f;
        float pim = 0.f;
        for (int t = 0; t < 39; t++) {
            float a = __shfl(qv, t, 64) * 0.5f;
            float c = cosf(a), s = sinf(a);
            float ur = __shfl_up(pr, 1, 64);
            float ui = __shfl_up(pim, 1, 64);
            if (lane == 0) { ur = 0.f; ui = 0.f; }
            float nr = c * pr - s * ui;
            float ni = c * pim + s * ur;
            pr = nr; pim = ni;
        }
        if (lane < NTAP) scr[lane] = pr;
    }
    __syncthreads();

    const float inv = 1.0f / sqrtf(red[0] + red[1] + red[2] + red[3]);
    float4* out4 = (float4*)rowp;

    // group g: outputs [i0, i0+8), i0 = tid*32 + g*8.
    // window w4[12] = logical float4 [8*tid+2g .. +11] = logical floats [i0, i0+48)
    //   (logical[p] = row[p-40]); out[i0+o] = sum_k taps[k]*WEL(40+o-k), idx in [1,47].
    #pragma unroll
    for (int g = 0; g < 4; g++) {
        float4 w4[12];
        #pragma unroll
        for (int t = 0; t < 12; t++) w4[t] = l4[SW4(8 * tid + 2 * g + t)];

        float av[8] = {};
        #pragma unroll
        for (int k = 0; k < NTAP; k++) {
            const float c = scr[k];             // LDS broadcast (free)
            #pragma unroll
            for (int o = 0; o < 8; o++) av[o] += c * WEL(40 + o - k);
        }
        const int f4 = 8 * tid + 2 * g;         // output float4 base = i0/4
        out4[f4]     = make_float4(inv * av[0], inv * av[1], inv * av[2], inv * av[3]);
        out4[f4 + 1] = make_float4(inv * av[4], inv * av[5], inv * av[6], inv * av[7]);
    }
}

// ---------------- launch ----------------
extern "C" void kernel_launch(void* const* d_in, const int* in_sizes, int n_in,
                              void* d_out, int out_size, void* d_ws, size_t ws_size,
                              hipStream_t stream) {
    const float* x  = (const float*)d_in[0];   // [1024][4096]
    const float* W  = (const float*)d_in[1];   // [8192][4096]
    const float* qp = (const float*)d_in[2];   // [39]
    float* out = (float*)d_out;                // [1024][8192] floats (Re of amps)
    long out_n = (long)out_size;

    const size_t need = (size_t)BATCH * IN_DIM * 2 + (size_t)HV * IN_DIM * 2;  // 72 MB

    if (ws_size >= need) {
        _Float16* xh = (_Float16*)d_ws;
        _Float16* wh = xh + (size_t)BATCH * IN_DIM;
        float* taps = nullptr;
        if (ws_size >= need + 256) {
            taps = (float*)((char*)d_ws + need);
            compute_taps<<<1, 64, 0, stream>>>(qp, taps);
        }
        int n4x = BATCH * IN_DIM / 4;          // 1,048,576
        int n4w = HV * IN_DIM / 4;             // 8,388,608
        cvt_f32_f16<<<n4x / 256, 256, 0, stream>>>((const float4*)x, (half4v*)xh, n4x);
        cvt_f32_f16<<<n4w / 256, 256, 0, stream>>>((const float4*)W, (half4v*)wh, n4w);
        dim3 grid2(HV / BN2, BATCH / BM2);     // (32, 8) = 256 blocks = 1/CU
        gemm_f16<<<grid2, 512, 0, stream>>>(xh, wh, out, out_n);
        norm_conv<<<BATCH, 256, 0, stream>>>(out, qp, taps, out_n);
    } else {
        float* taps = nullptr;
        if (ws_size >= 256) {
            taps = (float*)d_ws;
            compute_taps<<<1, 64, 0, stream>>>(qp, taps);
        }
        dim3 grid(HV / BN, BATCH / BM);        // (64, 8)
        gemm_f32in<<<grid, 256, 0, stream>>>(x, W, out, out_n);
        norm_conv<<<BATCH, 256, 0, stream>>>(out, qp, taps, out_n);
    }
}